// Round 2
// baseline (191.059 us; speedup 1.0000x reference)
//
#include <hip/hip_runtime.h>

// Ray termination probability scan along depth, split-D two-phase.
// voxels: [B=16, D=128, H=128, W=128] fp32, row-major (W contiguous).
// out[b, H-1-h, w] = sum_d o[b,d,h,w] * T_d,
//   o = clip(v, EPS, 1-EPS), T_0 = exp(EPS) (from the eps slab), T_d = prod_{k<d}(1-o_k).
//
// Scan is associative: split D into C=4 chunks of 32. Each chunk computes
//   a_c = sum_{d in c} o_d * prod_{k<d, in c}(1-o_k),  T_c = prod_{d in c}(1-o_d)
// then out = a_0 + T_0*a_1 + T_0*T_1*a_2 + T_0*T_1*T_2*a_3.
// C=4 quadruples wave count (4 -> 16 waves/CU) and cuts the serial load chain
// 128 -> 32, at +17 MB extra HBM traffic on a 134 MB problem.

#define EPS 1e-5f
#define EXP_EPS 1.0000100000500002f  // expf(1e-5f), applies to the d=0 term only

#define B_ 16
#define D_ 128
#define H_ 128
#define W_ 128
#define C_ 4
#define DC_ (D_ / C_)          // 32 depths per chunk
#define Q_ (B_ * H_ * W_ / 4)  // 65536 float4s per [B,H,W] field

__device__ __forceinline__ float clampo(float v) {
    return fminf(fmaxf(v, EPS), 1.0f - EPS);
}

// ws layout (float4 units): chunk c's A at (2c)*Q_ + idx, T at (2c+1)*Q_ + idx,
// idx = (b*H + h)*(W/4) + w4.

__global__ __launch_bounds__(128) void ray_chunk_kernel(const float* __restrict__ vox,
                                                        float4* __restrict__ ws) {
    const int w4 = threadIdx.x;                           // 0..31
    const int h  = blockIdx.x * blockDim.y + threadIdx.y; // blockDim.y = 4
    const int b  = blockIdx.y;
    const int c  = blockIdx.z;

    const float4* __restrict__ src =
        (const float4*)(vox + (((size_t)b * D_ + (size_t)c * DC_) * H_ + (size_t)h) * W_) + w4;
    const int dstride = H_ * W_ / 4;

    float a0 = 0.f, a1 = 0.f, a2 = 0.f, a3 = 0.f;
    float T0 = 1.f, T1 = 1.f, T2 = 1.f, T3 = 1.f;

    if (c == 0) {
        // d = 0 peeled: carries the exp(EPS) factor from the eps slab.
        float4 v = src[0];
        float o0 = clampo(v.x), o1 = clampo(v.y), o2 = clampo(v.z), o3 = clampo(v.w);
        a0 = o0 * EXP_EPS; a1 = o1 * EXP_EPS; a2 = o2 * EXP_EPS; a3 = o3 * EXP_EPS;
        T0 = 1.f - o0; T1 = 1.f - o1; T2 = 1.f - o2; T3 = 1.f - o3;
        #pragma unroll 8
        for (int d = 1; d < DC_; ++d) {
            float4 v2 = src[(size_t)d * dstride];
            float p0 = clampo(v2.x), p1 = clampo(v2.y), p2 = clampo(v2.z), p3 = clampo(v2.w);
            a0 = fmaf(p0, T0, a0); T0 *= (1.f - p0);
            a1 = fmaf(p1, T1, a1); T1 *= (1.f - p1);
            a2 = fmaf(p2, T2, a2); T2 *= (1.f - p2);
            a3 = fmaf(p3, T3, a3); T3 *= (1.f - p3);
        }
    } else {
        #pragma unroll 8
        for (int d = 0; d < DC_; ++d) {
            float4 v2 = src[(size_t)d * dstride];
            float p0 = clampo(v2.x), p1 = clampo(v2.y), p2 = clampo(v2.z), p3 = clampo(v2.w);
            a0 = fmaf(p0, T0, a0); T0 *= (1.f - p0);
            a1 = fmaf(p1, T1, a1); T1 *= (1.f - p1);
            a2 = fmaf(p2, T2, a2); T2 *= (1.f - p2);
            a3 = fmaf(p3, T3, a3); T3 *= (1.f - p3);
        }
    }

    const size_t idx = ((size_t)b * H_ + (size_t)h) * (W_ / 4) + w4;
    ws[(size_t)(2 * c) * Q_ + idx]     = make_float4(a0, a1, a2, a3);
    ws[(size_t)(2 * c + 1) * Q_ + idx] = make_float4(T0, T1, T2, T3);
}

__device__ __forceinline__ float4 f4_fma(float4 t, float4 r, float4 a) {
    // a + t * r, componentwise
    return make_float4(fmaf(t.x, r.x, a.x), fmaf(t.y, r.y, a.y),
                       fmaf(t.z, r.z, a.z), fmaf(t.w, r.w, a.w));
}

__global__ __launch_bounds__(256) void ray_combine_kernel(const float4* __restrict__ ws,
                                                          float4* __restrict__ out) {
    const int idx = blockIdx.x * 256 + threadIdx.x;  // 0..Q_-1
    const int w4s = W_ / 4;
    const int w4 = idx & (w4s - 1);
    const int hb = idx / w4s;
    const int h = hb & (H_ - 1);
    const int b = hb / H_;

    float4 a0 = ws[0 * Q_ + idx], t0 = ws[1 * Q_ + idx];
    float4 a1 = ws[2 * Q_ + idx], t1 = ws[3 * Q_ + idx];
    float4 a2 = ws[4 * Q_ + idx], t2 = ws[5 * Q_ + idx];
    float4 a3 = ws[6 * Q_ + idx];

    float4 r = f4_fma(t2, a3, a2);
    r = f4_fma(t1, r, a1);
    r = f4_fma(t0, r, a0);

    // vertical flip along H on output
    out[((size_t)b * H_ + (size_t)(H_ - 1 - h)) * w4s + w4] = r;
}

extern "C" void kernel_launch(void* const* d_in, const int* in_sizes, int n_in,
                              void* d_out, int out_size, void* d_ws, size_t ws_size,
                              hipStream_t stream) {
    const float* vox = (const float*)d_in[0];
    float4* ws = (float4*)d_ws;
    float4* out = (float4*)d_out;

    dim3 block1(32, 4, 1);              // 128 threads = 2 waves
    dim3 grid1(H_ / 4, B_, C_);         // 32 x 16 x 4 = 2048 blocks
    ray_chunk_kernel<<<grid1, block1, 0, stream>>>(vox, ws);

    ray_combine_kernel<<<Q_ / 256, 256, 0, stream>>>(ws, out);
}

// Round 3
// 185.990 us; speedup vs baseline: 1.0273x; 1.0273x over previous
//
#include <hip/hip_runtime.h>

// Ray termination probability scan along depth, split-D within a block.
// voxels: [B=16, D=128, H=128, W=128] fp32, row-major (W contiguous).
// out[b, H-1-h, w] = sum_d o[b,d,h,w] * T_d,
//   o = clip(v, EPS, 1-EPS), T_0 = exp(EPS) (eps slab), T_d = prod_{k<d}(1-o_k).
//
// Scan is associative: D split into C=4 chunks of 32, one chunk per threadIdx.z.
// Chunk partials (a_c, T_c) combine as out = a0 + T0*(a1 + T1*(a2 + T2*a3)).
// Split lives INSIDE the block (LDS combine) -> zero extra HBM traffic
// (round-2's ws round-trip cost +7us), while keeping 16 waves/CU and a
// 32-deep serial load chain (round-1 had 4 waves/CU, 128-deep).
// Thread layout (32,2,4): flat = w4 + 32*h' + 64*c, so wave 0 == chunk 0 ->
// combine branch is wave-uniform, no divergence.

#define EPS 1e-5f
#define EXP_EPS 1.0000100000500002f  // expf(1e-5f), applies to the d=0 term only

#define B_ 16
#define D_ 128
#define H_ 128
#define W_ 128
#define C_ 4
#define DC_ (D_ / C_)   // 32 depths per chunk
#define BY_ 2           // h-rows per block

__device__ __forceinline__ float clampo(float v) {
    return fminf(fmaxf(v, EPS), 1.0f - EPS);
}

__device__ __forceinline__ float4 f4_fma(float4 t, float4 r, float4 a) {
    // a + t*r componentwise
    return make_float4(fmaf(t.x, r.x, a.x), fmaf(t.y, r.y, a.y),
                       fmaf(t.z, r.z, a.z), fmaf(t.w, r.w, a.w));
}

__global__ __launch_bounds__(256) void ray_term_kernel(const float* __restrict__ vox,
                                                       float* __restrict__ out) {
    const int w4 = threadIdx.x;                     // 0..31
    const int hy = threadIdx.y;                     // 0..1
    const int c  = threadIdx.z;                     // 0..3 depth chunk
    const int h  = blockIdx.x * BY_ + hy;
    const int b  = blockIdx.y;

    const float4* __restrict__ src =
        (const float4*)(vox + (((size_t)b * D_ + (size_t)c * DC_) * H_ + (size_t)h) * W_) + w4;
    const int dstride = H_ * W_ / 4;  // float4 stride between depth slices

    float a0, a1, a2, a3, T0, T1, T2, T3;
    int dstart;
    if (c == 0) {  // wave-uniform: wave 0 is exactly c==0
        // d = 0 peeled: carries the exp(EPS) factor from the eps slab.
        float4 v = src[0];
        float o0 = clampo(v.x), o1 = clampo(v.y), o2 = clampo(v.z), o3 = clampo(v.w);
        a0 = o0 * EXP_EPS; a1 = o1 * EXP_EPS; a2 = o2 * EXP_EPS; a3 = o3 * EXP_EPS;
        T0 = 1.f - o0; T1 = 1.f - o1; T2 = 1.f - o2; T3 = 1.f - o3;
        dstart = 1;
    } else {
        a0 = a1 = a2 = a3 = 0.f;
        T0 = T1 = T2 = T3 = 1.f;
        dstart = 0;
    }

    #pragma unroll 8
    for (int d = dstart; d < DC_; ++d) {
        float4 v = src[(size_t)d * dstride];
        float p0 = clampo(v.x), p1 = clampo(v.y), p2 = clampo(v.z), p3 = clampo(v.w);
        a0 = fmaf(p0, T0, a0); T0 *= (1.f - p0);
        a1 = fmaf(p1, T1, a1); T1 *= (1.f - p1);
        a2 = fmaf(p2, T2, a2); T2 *= (1.f - p2);
        a3 = fmaf(p3, T3, a3); T3 *= (1.f - p3);
    }

    // Publish chunk partials: a for c=1..3, T for c=1..2 (T of c=3 unused).
    __shared__ float4 a_l[C_ - 1][BY_][32];
    __shared__ float4 t_l[C_ - 2][BY_][32];
    if (c >= 1) {
        a_l[c - 1][hy][w4] = make_float4(a0, a1, a2, a3);
        if (c <= 2) t_l[c - 1][hy][w4] = make_float4(T0, T1, T2, T3);
    }
    __syncthreads();

    if (c == 0) {  // wave 0 combines and stores
        float4 A1 = a_l[0][hy][w4], TT1 = t_l[0][hy][w4];
        float4 A2 = a_l[1][hy][w4], TT2 = t_l[1][hy][w4];
        float4 A3 = a_l[2][hy][w4];
        float4 r = f4_fma(TT2, A3, A2);       // a2 + T2*a3
        r = f4_fma(TT1, r, A1);               // a1 + T1*(...)
        float4 myA = make_float4(a0, a1, a2, a3);
        float4 myT = make_float4(T0, T1, T2, T3);
        r = f4_fma(myT, r, myA);              // a0 + T0*(...)

        // vertical flip along H on output
        float* __restrict__ dst =
            out + ((size_t)b * H_ + (size_t)(H_ - 1 - h)) * W_ + 4 * w4;
        *(float4*)dst = r;
    }
}

extern "C" void kernel_launch(void* const* d_in, const int* in_sizes, int n_in,
                              void* d_out, int out_size, void* d_ws, size_t ws_size,
                              hipStream_t stream) {
    const float* vox = (const float*)d_in[0];
    float* out = (float*)d_out;
    dim3 block(32, BY_, C_);        // 256 threads = 4 waves, wave==chunk
    dim3 grid(H_ / BY_, B_, 1);     // 64 x 16 = 1024 blocks -> 16 waves/CU
    ray_term_kernel<<<grid, block, 0, stream>>>(vox, out);
}

// Round 4
// 184.009 us; speedup vs baseline: 1.0383x; 1.0108x over previous
//
#include <hip/hip_runtime.h>

// Ray termination probability scan along depth.
// voxels: [B=16, D=128, H=128, W=128] fp32, row-major (W contiguous).
// out[b, H-1-h, w] = sum_{d} o[b,d,h,w] * T_d,
//   o = clip(v, EPS, 1-EPS), T_0 = exp(EPS), T_d = prod_{k<d}(1-o_k).
// Direct-product form of the reference's exp(cumsum(log(1-o))) -- identical math.
//
// Bench history: this single-dispatch form = 183.9 us total (R1).
// Block-level D-split (R2) = 191.1 (+ws round-trip +dispatch); in-block
// D-split w/ LDS combine (R3) = 186.0 (+sync/epilogue overhead). Both
// parallelism boosts were neutral-to-negative -> kernel is HBM-BW-bound at
// 4 waves/CU already (8 MB in flight >> 2.6 MB BW*latency product).
// Irreducible traffic: 134 MB read + 1 MB write ~= 20 us at measured 6.9 TB/s;
// the rest of dur_us is harness reset work (537 MB ws poison = 77.5 us etc).

#define EPS 1e-5f
#define EXP_EPS 1.0000100000500002f  // expf(1e-5f)

#define B_ 16
#define D_ 128
#define H_ 128
#define W_ 128

__device__ __forceinline__ float clampo(float v) {
    return fminf(fmaxf(v, EPS), 1.0f - EPS);
}

__global__ __launch_bounds__(128) void ray_term_kernel(const float* __restrict__ vox,
                                                       float* __restrict__ out) {
    const int w4 = threadIdx.x;                          // 0..31 -> w = 4*w4..4*w4+3
    const int h  = blockIdx.x * blockDim.y + threadIdx.y; // blockDim.y = 4
    const int b  = blockIdx.y;

    // base points at [b, d=0, h, 4*w4]
    const float4* __restrict__ src =
        (const float4*)(vox + ((size_t)b * D_ * H_ + (size_t)h) * W_) + w4;
    const int dstride = H_ * W_ / 4;  // float4 stride between depth slices

    // d = 0 peeled: carries the exp(EPS) factor from the eps slab.
    float4 v0 = src[0];
    float o0 = clampo(v0.x), o1 = clampo(v0.y), o2 = clampo(v0.z), o3 = clampo(v0.w);
    float a0 = o0 * EXP_EPS, a1 = o1 * EXP_EPS, a2 = o2 * EXP_EPS, a3 = o3 * EXP_EPS;
    float T0 = 1.0f - o0, T1 = 1.0f - o1, T2 = 1.0f - o2, T3 = 1.0f - o3;

    #pragma unroll 8
    for (int d = 1; d < D_; ++d) {
        float4 v = src[(size_t)d * dstride];
        o0 = clampo(v.x); o1 = clampo(v.y); o2 = clampo(v.z); o3 = clampo(v.w);
        a0 = fmaf(o0, T0, a0); T0 *= (1.0f - o0);
        a1 = fmaf(o1, T1, a1); T1 *= (1.0f - o1);
        a2 = fmaf(o2, T2, a2); T2 *= (1.0f - o2);
        a3 = fmaf(o3, T3, a3); T3 *= (1.0f - o3);
    }

    // vertical flip along H on output
    float* __restrict__ dst =
        out + ((size_t)b * H_ + (size_t)(H_ - 1 - h)) * W_ + 4 * w4;
    *(float4*)dst = make_float4(a0, a1, a2, a3);
}

extern "C" void kernel_launch(void* const* d_in, const int* in_sizes, int n_in,
                              void* d_out, int out_size, void* d_ws, size_t ws_size,
                              hipStream_t stream) {
    const float* vox = (const float*)d_in[0];
    float* out = (float*)d_out;
    dim3 block(32, 4, 1);           // 128 threads = 2 waves
    dim3 grid(H_ / 4, B_, 1);       // 32 x 16 = 512 blocks, 2 blocks/CU
    ray_term_kernel<<<grid, block, 0, stream>>>(vox, out);
}